// Round 26
// baseline (77.003 us; speedup 1.0000x reference)
//
#include <hip/hip_runtime.h>
#include <hip/hip_fp16.h>

#define Nn 100000
#define Ee 1600000
#define HID 128
#define IN_DIM 5

// dst buckets: 256 nodes, 391 buckets
#define SH 8
#define BSZ 256
#define NB 391            // ceil(100000/256)
#define BCAP 4608         // per-bucket capacity (mean ~4092, sigma ~64 -> +8 sigma)

#define PCHUNK 3125       // edges per partition block
#define PBLK 512          // 512 * 3125 = 1,600,000 exactly
#define MAXK 7            // ceil(3125/512)

typedef float f32x4 __attribute__((ext_vector_type(4)));
union F2H { float f; __half2 h; };

// ---------- kernel 0: zero the bucket counters ----------
__global__ void zero_kernel(int* __restrict__ bcnt) {
    if (threadIdx.x < NB) bcnt[threadIdx.x] = 0;
}

// ---------- kernel 1: single-pass register-staged partition ----------
__global__ __launch_bounds__(512) void partition_kernel(const int* __restrict__ src,
                                                        const int* __restrict__ dst,
                                                        unsigned int* __restrict__ recs,
                                                        int* __restrict__ bcnt) {
    __shared__ unsigned int stage[PCHUNK];     // 12.5 KB
    __shared__ unsigned short bstage[PCHUNK];  // 6.3 KB
    __shared__ int hist[NB + 1];
    __shared__ int histS[NB + 1];
    __shared__ int cur[NB];
    __shared__ int gbase[NB];
    __shared__ int wsum[8];
    int tid = threadIdx.x;
    int e0 = blockIdx.x * PCHUNK;
    for (int i = tid; i <= NB; i += 512) hist[i] = 0;
    __syncthreads();
    int rb[MAXK];
    unsigned int rv[MAXK];
    #pragma unroll
    for (int k = 0; k < MAXK; ++k) {
        int idx = tid + k * 512;
        rb[k] = -1;
        if (idx < PCHUNK) {
            int e = e0 + idx;
            int d = dst[e], s = src[e];
            rb[k] = d >> SH;
            rv[k] = ((unsigned int)(d & (BSZ - 1)) << 17) | (unsigned int)s;
            atomicAdd(&hist[rb[k]], 1);
        }
    }
    __syncthreads();
    int v = (tid < NB) ? hist[tid] : 0;
    int lane = tid & 63, wid = tid >> 6;
    int sc = v;
    #pragma unroll
    for (int ofs = 1; ofs < 64; ofs <<= 1) {
        int t = __shfl_up(sc, ofs, 64);
        if (lane >= ofs) sc += t;
    }
    if (lane == 63) wsum[wid] = sc;
    __syncthreads();
    int wpre = 0;
    #pragma unroll
    for (int w = 0; w < 8; ++w)
        if (w < wid) wpre += wsum[w];
    int excl = wpre + sc - v;
    if (tid < NB) {
        histS[tid] = excl;
        cur[tid] = excl;
        gbase[tid] = atomicAdd(&bcnt[tid], v);
    }
    __syncthreads();
    #pragma unroll
    for (int k = 0; k < MAXK; ++k)
        if (rb[k] >= 0) {
            int slot = atomicAdd(&cur[rb[k]], 1);
            stage[slot] = rv[k];
            bstage[slot] = (unsigned short)rb[k];
        }
    __syncthreads();
    for (int i = tid; i < PCHUNK; i += 512) {
        int b = bstage[i];
        recs[(size_t)b * BCAP + gbase[b] + (i - histS[b])] = stage[i];
    }
}

// ---------- kernel 2: per-bucket counting sort + LDS-staged output ----------
__global__ __launch_bounds__(BSZ) void sortk_kernel(const unsigned int* __restrict__ recs,
                                                    const int* __restrict__ bcnt,
                                                    const float* __restrict__ x,
                                                    int* __restrict__ degc,
                                                    unsigned int* __restrict__ nodeoff,
                                                    unsigned int* __restrict__ ssrc,
                                                    float* __restrict__ dinv,
                                                    f32x4* __restrict__ xd16) {
    __shared__ int cnt[BSZ];
    __shared__ int cur[BSZ];
    __shared__ int wsum[BSZ / 64];
    __shared__ unsigned int lstage[BCAP];    // 18.4 KB sorted values
    int b = blockIdx.x, tid = threadIdx.x;
    int n = bcnt[b];
    cnt[tid] = 0;
    __syncthreads();
    const unsigned int* R = recs + (size_t)b * BCAP;
    for (int i = tid; i < n; i += BSZ)
        atomicAdd(&cnt[R[i] >> 17], 1);
    __syncthreads();
    int v = cnt[tid];
    int lane = tid & 63, wid = tid >> 6;
    int sc = v;
    #pragma unroll
    for (int ofs = 1; ofs < 64; ofs <<= 1) {
        int t = __shfl_up(sc, ofs, 64);
        if (lane >= ofs) sc += t;
    }
    if (lane == 63) wsum[wid] = sc;
    __syncthreads();
    int wpre = 0;
    #pragma unroll
    for (int w = 0; w < BSZ / 64; ++w)
        if (w < wid) wpre += wsum[w];
    int excl = wpre + sc - v;
    cur[tid] = excl;
    int g = (b << SH) + tid;
    if (g < Nn) {
        degc[g] = v;
        nodeoff[g] = (unsigned int)(b * BCAP + excl);
        float di = rsqrtf((float)v + 1.0f);
        dinv[g] = di;
        f32x4 o;
        o.x = x[g * IN_DIM + 0] * di;
        o.y = x[g * IN_DIM + 1] * di;
        o.z = x[g * IN_DIM + 2] * di;
        F2H u;
        u.h = __floats2half2_rn(x[g * IN_DIM + 3] * di, x[g * IN_DIM + 4] * di);
        o.w = u.f;
        xd16[g] = o;
    }
    __syncthreads();
    for (int i = tid; i < n; i += BSZ) {
        unsigned int r = R[i];
        int pos = atomicAdd(&cur[r >> 17], 1);
        lstage[pos] = r & 0x1FFFFu;
    }
    __syncthreads();
    unsigned int* O = ssrc + (size_t)b * BCAP;
    for (int i = tid; i < n; i += BSZ) O[i] = lstage[i];
}

// ---------- kernel 3: layer-1, quad-lane per node ----------
__global__ __launch_bounds__(256) void gcn1_kernel(const unsigned int* __restrict__ ssrc,
                                                   const unsigned int* __restrict__ nodeoff,
                                                   const int* __restrict__ degc,
                                                   const f32x4* __restrict__ xd16,
                                                   const float* __restrict__ dinv,
                                                   const float* __restrict__ W1,
                                                   const float* __restrict__ b1,
                                                   const float* __restrict__ W2,
                                                   float* __restrict__ h2d) {
    __shared__ float w1s[IN_DIM * HID];
    __shared__ float w2s[HID], b1s[HID];
    int tid = threadIdx.x;
    for (int j = tid; j < IN_DIM * HID; j += 256) w1s[j] = W1[j];
    if (tid < HID) { w2s[tid] = W2[tid]; b1s[tid] = b1[tid]; }
    __syncthreads();
    int q = tid & 3;
    int nd = blockIdx.x * 64 + (tid >> 2);
    if (nd >= Nn) return;
    unsigned int off = nodeoff[nd];
    int len = degc[nd];
    float a0 = 0.f, a1 = 0.f, a2 = 0.f, a3 = 0.f, a4 = 0.f;
    int i = q;
    for (; i + 4 < len; i += 8) {
        unsigned int s0 = ssrc[off + i], s1 = ssrc[off + i + 4];
        f32x4 v0 = xd16[s0], v1 = xd16[s1];
        F2H u0, u1;
        u0.f = v0.w; u1.f = v1.w;
        float2 e0 = __half22float2(u0.h), e1 = __half22float2(u1.h);
        a0 += v0.x + v1.x;
        a1 += v0.y + v1.y;
        a2 += v0.z + v1.z;
        a3 += e0.x + e1.x;
        a4 += e0.y + e1.y;
    }
    if (i < len) {
        unsigned int s = ssrc[off + i];
        f32x4 v = xd16[s];
        F2H u; u.f = v.w; float2 e = __half22float2(u.h);
        a0 += v.x; a1 += v.y; a2 += v.z; a3 += e.x; a4 += e.y;
    }
    #pragma unroll
    for (int m = 1; m <= 2; m <<= 1) {
        a0 += __shfl_xor(a0, m, 64);
        a1 += __shfl_xor(a1, m, 64);
        a2 += __shfl_xor(a2, m, 64);
        a3 += __shfl_xor(a3, m, 64);
        a4 += __shfl_xor(a4, m, 64);
    }
    float di = dinv[nd];
    f32x4 sv = xd16[nd];
    F2H su; su.f = sv.w; float2 se = __half22float2(su.h);
    a0 = (a0 + sv.x) * di;
    a1 = (a1 + sv.y) * di;
    a2 = (a2 + sv.z) * di;
    a3 = (a3 + se.x) * di;
    a4 = (a4 + se.y) * di;
    float accp = 0.f;
    #pragma unroll
    for (int f0 = 0; f0 < HID; f0 += 4) {
        int f = f0 + q;
        float v = b1s[f] + a0 * w1s[f] + a1 * w1s[HID + f] + a2 * w1s[2 * HID + f]
                + a3 * w1s[3 * HID + f] + a4 * w1s[4 * HID + f];
        accp += fmaxf(v, 0.f) * w2s[f];
    }
    accp += __shfl_xor(accp, 1, 64);
    accp += __shfl_xor(accp, 2, 64);
    if (q == 0) h2d[nd] = accp * di;
}

// ---------- kernel 4: layer-2, quad-lane per node ----------
__global__ __launch_bounds__(256) void gcn2_kernel(const unsigned int* __restrict__ ssrc,
                                                   const unsigned int* __restrict__ nodeoff,
                                                   const int* __restrict__ degc,
                                                   const float* __restrict__ h2d,
                                                   const float* __restrict__ dinv,
                                                   const float* __restrict__ b2,
                                                   float* __restrict__ out) {
    int tid = threadIdx.x;
    int q = tid & 3;
    int nd = blockIdx.x * 64 + (tid >> 2);
    if (nd >= Nn) return;
    unsigned int off = nodeoff[nd];
    int len = degc[nd];
    float s = 0.f;
    int i = q;
    for (; i + 4 < len; i += 8) {
        float t0 = h2d[ssrc[off + i]];
        float t1 = h2d[ssrc[off + i + 4]];
        s += t0 + t1;
    }
    if (i < len) s += h2d[ssrc[off + i]];
    s += __shfl_xor(s, 1, 64);
    s += __shfl_xor(s, 2, 64);
    if (q == 0) out[nd] = (s + h2d[nd]) * dinv[nd] + b2[0];
}

extern "C" void kernel_launch(void* const* d_in, const int* in_sizes, int n_in,
                              void* d_out, int out_size, void* d_ws, size_t ws_size,
                              hipStream_t stream) {
    const float* x  = (const float*)d_in[0];
    const int*   ei = (const int*)d_in[1];     // [2, E]: src row then dst row
    const float* W1 = (const float*)d_in[2];
    const float* b1 = (const float*)d_in[3];
    const float* W2 = (const float*)d_in[4];
    const float* b2 = (const float*)d_in[5];
    const int* src = ei;
    const int* dst = ei + Ee;
    float* out = (float*)d_out;

    float* dinv = (float*)d_ws;                      // N floats
    f32x4* xd16 = (f32x4*)(dinv + Nn);               // N f32x4 (1.6 MB)
    float* h2d  = (float*)(xd16 + Nn);               // N
    int* degc   = (int*)(h2d + Nn);                  // N ints
    unsigned int* nodeoff = (unsigned int*)(degc + Nn);          // N u32
    unsigned int* recs = nodeoff + Nn;               // NB*BCAP u32 (7.2 MB)
    unsigned int* ssrc = recs + (size_t)NB * BCAP;   // NB*BCAP u32 (7.2 MB)
    int* bcnt = (int*)(ssrc + (size_t)NB * BCAP);    // NB ints
    // probe scratch (written only by the duplicate sortk)
    float* dinv2 = (float*)(bcnt + NB + 1);          // N
    f32x4* xd16_2 = (f32x4*)(dinv2 + Nn);            // 4N
    int* degc2 = (int*)(xd16_2 + Nn);                // N
    unsigned int* nodeoff2 = (unsigned int*)(degc2 + Nn);        // N
    unsigned int* ssrc2 = nodeoff2 + Nn;             // NB*BCAP (7.2 MB)

    zero_kernel<<<1, 512, 0, stream>>>(bcnt);
    partition_kernel<<<PBLK, 512, 0, stream>>>(src, dst, recs, bcnt);
    sortk_kernel<<<NB, BSZ, 0, stream>>>(recs, bcnt, x, degc, nodeoff, ssrc, dinv, xd16);
    gcn1_kernel<<<(Nn + 63) / 64, 256, 0, stream>>>(ssrc, nodeoff, degc, xd16, dinv,
                                                    W1, b1, W2, h2d);
    gcn2_kernel<<<(Nn + 63) / 64, 256, 0, stream>>>(ssrc, nodeoff, degc, h2d, dinv, b2, out);
    // measurement probe: duplicate sortk into scratch (after pipeline; no effect on out)
    sortk_kernel<<<NB, BSZ, 0, stream>>>(recs, bcnt, x, degc2, nodeoff2, ssrc2, dinv2, xd16_2);
}

// Round 28
// 66.615 us; speedup vs baseline: 1.1559x; 1.1559x over previous
//
#include <hip/hip_runtime.h>
#include <hip/hip_fp16.h>

#define Nn 100000
#define Ee 1600000
#define HID 128
#define IN_DIM 5

// dst buckets: 256 nodes, 391 buckets
#define SH 8
#define BSZ 256
#define NB 391            // ceil(100000/256)
#define BCAP 4608         // per-bucket capacity (mean ~4092, sigma ~64 -> +8 sigma)

#define PCHUNK 3125       // edges per partition block
#define PBLK 512          // 512 * 3125 = 1,600,000 exactly
#define MAXK 7            // ceil(3125/512)

typedef float f32x4 __attribute__((ext_vector_type(4)));
union F2H { float f; __half2 h; };

// ---------- kernel 0: zero the bucket counters ----------
__global__ void zero_kernel(int* __restrict__ bcnt) {
    if (threadIdx.x < NB) bcnt[threadIdx.x] = 0;
}

// ---------- kernel 1: single-pass register-staged partition ----------
// rec = (d_local << 17) | src   (src < 2^17, d_local < 2^8)
__global__ __launch_bounds__(512) void partition_kernel(const int* __restrict__ src,
                                                        const int* __restrict__ dst,
                                                        unsigned int* __restrict__ recs,
                                                        int* __restrict__ bcnt) {
    __shared__ unsigned int stage[PCHUNK];     // 12.5 KB
    __shared__ unsigned short bstage[PCHUNK];  // 6.3 KB
    __shared__ int hist[NB + 1];
    __shared__ int histS[NB + 1];
    __shared__ int cur[NB];
    __shared__ int gbase[NB];
    __shared__ int wsum[8];
    int tid = threadIdx.x;
    int e0 = blockIdx.x * PCHUNK;
    for (int i = tid; i <= NB; i += 512) hist[i] = 0;
    __syncthreads();
    int rb[MAXK];
    unsigned int rv[MAXK];
    #pragma unroll
    for (int k = 0; k < MAXK; ++k) {
        int idx = tid + k * 512;
        rb[k] = -1;
        if (idx < PCHUNK) {
            int e = e0 + idx;
            int d = dst[e], s = src[e];
            rb[k] = d >> SH;
            rv[k] = ((unsigned int)(d & (BSZ - 1)) << 17) | (unsigned int)s;
            atomicAdd(&hist[rb[k]], 1);
        }
    }
    __syncthreads();
    int v = (tid < NB) ? hist[tid] : 0;
    int lane = tid & 63, wid = tid >> 6;
    int sc = v;
    #pragma unroll
    for (int ofs = 1; ofs < 64; ofs <<= 1) {
        int t = __shfl_up(sc, ofs, 64);
        if (lane >= ofs) sc += t;
    }
    if (lane == 63) wsum[wid] = sc;
    __syncthreads();
    int wpre = 0;
    #pragma unroll
    for (int w = 0; w < 8; ++w)
        if (w < wid) wpre += wsum[w];
    int excl = wpre + sc - v;
    if (tid < NB) {
        histS[tid] = excl;
        cur[tid] = excl;
        gbase[tid] = atomicAdd(&bcnt[tid], v);
    }
    __syncthreads();
    #pragma unroll
    for (int k = 0; k < MAXK; ++k)
        if (rb[k] >= 0) {
            int slot = atomicAdd(&cur[rb[k]], 1);
            stage[slot] = rv[k];
            bstage[slot] = (unsigned short)rb[k];
        }
    __syncthreads();
    for (int i = tid; i < PCHUNK; i += 512) {
        int b = bstage[i];
        recs[(size_t)b * BCAP + gbase[b] + (i - histS[b])] = stage[i];
    }
}

// ---------- kernel 2: per-bucket counting sort + LDS-staged output ----------
__global__ __launch_bounds__(BSZ) void sortk_kernel(const unsigned int* __restrict__ recs,
                                                    const int* __restrict__ bcnt,
                                                    const float* __restrict__ x,
                                                    int* __restrict__ degc,
                                                    unsigned int* __restrict__ nodeoff,
                                                    unsigned int* __restrict__ ssrc,
                                                    float* __restrict__ dinv,
                                                    f32x4* __restrict__ xd16) {
    __shared__ int cnt[BSZ];
    __shared__ int cur[BSZ];
    __shared__ int wsum[BSZ / 64];
    __shared__ unsigned int lstage[BCAP];    // 18.4 KB sorted values
    int b = blockIdx.x, tid = threadIdx.x;
    int n = bcnt[b];
    cnt[tid] = 0;
    __syncthreads();
    const unsigned int* R = recs + (size_t)b * BCAP;
    for (int i = tid; i < n; i += BSZ)
        atomicAdd(&cnt[R[i] >> 17], 1);
    __syncthreads();
    int v = cnt[tid];
    int lane = tid & 63, wid = tid >> 6;
    int sc = v;
    #pragma unroll
    for (int ofs = 1; ofs < 64; ofs <<= 1) {
        int t = __shfl_up(sc, ofs, 64);
        if (lane >= ofs) sc += t;
    }
    if (lane == 63) wsum[wid] = sc;
    __syncthreads();
    int wpre = 0;
    #pragma unroll
    for (int w = 0; w < BSZ / 64; ++w)
        if (w < wid) wpre += wsum[w];
    int excl = wpre + sc - v;
    cur[tid] = excl;
    int g = (b << SH) + tid;
    if (g < Nn) {
        degc[g] = v;
        nodeoff[g] = (unsigned int)(b * BCAP + excl);
        float di = rsqrtf((float)v + 1.0f);
        dinv[g] = di;
        f32x4 o;
        o.x = x[g * IN_DIM + 0] * di;
        o.y = x[g * IN_DIM + 1] * di;
        o.z = x[g * IN_DIM + 2] * di;
        F2H u;
        u.h = __floats2half2_rn(x[g * IN_DIM + 3] * di, x[g * IN_DIM + 4] * di);
        o.w = u.f;
        xd16[g] = o;
    }
    __syncthreads();
    for (int i = tid; i < n; i += BSZ) {
        unsigned int r = R[i];
        int pos = atomicAdd(&cur[r >> 17], 1);
        lstage[pos] = r & 0x1FFFFu;
    }
    __syncthreads();
    unsigned int* O = ssrc + (size_t)b * BCAP;
    for (int i = tid; i < n; i += BSZ) O[i] = lstage[i];
}

// ---------- kernel 3: layer-1, quad-lane per node ----------
__global__ __launch_bounds__(256) void gcn1_kernel(const unsigned int* __restrict__ ssrc,
                                                   const unsigned int* __restrict__ nodeoff,
                                                   const int* __restrict__ degc,
                                                   const f32x4* __restrict__ xd16,
                                                   const float* __restrict__ dinv,
                                                   const float* __restrict__ W1,
                                                   const float* __restrict__ b1,
                                                   const float* __restrict__ W2,
                                                   float* __restrict__ h2d) {
    __shared__ float w1s[IN_DIM * HID];
    __shared__ float w2s[HID], b1s[HID];
    int tid = threadIdx.x;
    for (int j = tid; j < IN_DIM * HID; j += 256) w1s[j] = W1[j];
    if (tid < HID) { w2s[tid] = W2[tid]; b1s[tid] = b1[tid]; }
    __syncthreads();
    int q = tid & 3;
    int nd = blockIdx.x * 64 + (tid >> 2);
    if (nd >= Nn) return;
    unsigned int off = nodeoff[nd];
    int len = degc[nd];
    float a0 = 0.f, a1 = 0.f, a2 = 0.f, a3 = 0.f, a4 = 0.f;
    int i = q;
    for (; i + 4 < len; i += 8) {
        unsigned int s0 = ssrc[off + i], s1 = ssrc[off + i + 4];
        f32x4 v0 = xd16[s0], v1 = xd16[s1];
        F2H u0, u1;
        u0.f = v0.w; u1.f = v1.w;
        float2 e0 = __half22float2(u0.h), e1 = __half22float2(u1.h);
        a0 += v0.x + v1.x;
        a1 += v0.y + v1.y;
        a2 += v0.z + v1.z;
        a3 += e0.x + e1.x;
        a4 += e0.y + e1.y;
    }
    if (i < len) {
        unsigned int s = ssrc[off + i];
        f32x4 v = xd16[s];
        F2H u; u.f = v.w; float2 e = __half22float2(u.h);
        a0 += v.x; a1 += v.y; a2 += v.z; a3 += e.x; a4 += e.y;
    }
    #pragma unroll
    for (int m = 1; m <= 2; m <<= 1) {
        a0 += __shfl_xor(a0, m, 64);
        a1 += __shfl_xor(a1, m, 64);
        a2 += __shfl_xor(a2, m, 64);
        a3 += __shfl_xor(a3, m, 64);
        a4 += __shfl_xor(a4, m, 64);
    }
    float di = dinv[nd];
    f32x4 sv = xd16[nd];
    F2H su; su.f = sv.w; float2 se = __half22float2(su.h);
    a0 = (a0 + sv.x) * di;
    a1 = (a1 + sv.y) * di;
    a2 = (a2 + sv.z) * di;
    a3 = (a3 + se.x) * di;
    a4 = (a4 + se.y) * di;
    float accp = 0.f;
    #pragma unroll
    for (int f0 = 0; f0 < HID; f0 += 4) {
        int f = f0 + q;
        float v = b1s[f] + a0 * w1s[f] + a1 * w1s[HID + f] + a2 * w1s[2 * HID + f]
                + a3 * w1s[3 * HID + f] + a4 * w1s[4 * HID + f];
        accp += fmaxf(v, 0.f) * w2s[f];
    }
    accp += __shfl_xor(accp, 1, 64);
    accp += __shfl_xor(accp, 2, 64);
    if (q == 0) h2d[nd] = accp * di;
}

// ---------- kernel 4: layer-2, quad-lane per node ----------
__global__ __launch_bounds__(256) void gcn2_kernel(const unsigned int* __restrict__ ssrc,
                                                   const unsigned int* __restrict__ nodeoff,
                                                   const int* __restrict__ degc,
                                                   const float* __restrict__ h2d,
                                                   const float* __restrict__ dinv,
                                                   const float* __restrict__ b2,
                                                   float* __restrict__ out) {
    int tid = threadIdx.x;
    int q = tid & 3;
    int nd = blockIdx.x * 64 + (tid >> 2);
    if (nd >= Nn) return;
    unsigned int off = nodeoff[nd];
    int len = degc[nd];
    float s = 0.f;
    int i = q;
    for (; i + 4 < len; i += 8) {
        float t0 = h2d[ssrc[off + i]];
        float t1 = h2d[ssrc[off + i + 4]];
        s += t0 + t1;
    }
    if (i < len) s += h2d[ssrc[off + i]];
    s += __shfl_xor(s, 1, 64);
    s += __shfl_xor(s, 2, 64);
    if (q == 0) out[nd] = (s + h2d[nd]) * dinv[nd] + b2[0];
}

extern "C" void kernel_launch(void* const* d_in, const int* in_sizes, int n_in,
                              void* d_out, int out_size, void* d_ws, size_t ws_size,
                              hipStream_t stream) {
    const float* x  = (const float*)d_in[0];
    const int*   ei = (const int*)d_in[1];     // [2, E]: src row then dst row
    const float* W1 = (const float*)d_in[2];
    const float* b1 = (const float*)d_in[3];
    const float* W2 = (const float*)d_in[4];
    const float* b2 = (const float*)d_in[5];
    const int* src = ei;
    const int* dst = ei + Ee;
    float* out = (float*)d_out;

    float* dinv = (float*)d_ws;                      // N floats
    f32x4* xd16 = (f32x4*)(dinv + Nn);               // N f32x4 (1.6 MB)
    float* h2d  = (float*)(xd16 + Nn);               // N
    int* degc   = (int*)(h2d + Nn);                  // N ints
    unsigned int* nodeoff = (unsigned int*)(degc + Nn);          // N u32
    unsigned int* recs = nodeoff + Nn;               // NB*BCAP u32 (7.2 MB)
    unsigned int* ssrc = recs + (size_t)NB * BCAP;   // NB*BCAP u32 (7.2 MB)
    int* bcnt = (int*)(ssrc + (size_t)NB * BCAP);    // NB ints

    zero_kernel<<<1, 512, 0, stream>>>(bcnt);
    partition_kernel<<<PBLK, 512, 0, stream>>>(src, dst, recs, bcnt);
    sortk_kernel<<<NB, BSZ, 0, stream>>>(recs, bcnt, x, degc, nodeoff, ssrc, dinv, xd16);
    gcn1_kernel<<<(Nn + 63) / 64, 256, 0, stream>>>(ssrc, nodeoff, degc, xd16, dinv,
                                                    W1, b1, W2, h2d);
    gcn2_kernel<<<(Nn + 63) / 64, 256, 0, stream>>>(ssrc, nodeoff, degc, h2d, dinv, b2, out);
}